// Round 1
// baseline (44.600 us; speedup 1.0000x reference)
//
#include <hip/hip_runtime.h>
#include <cmath>

// Spherization: per row of x[B,512]:
//   ang_i   = (PI - 2*phiL) * sigmoid(scaling*x_i) + phiL        (in (0,pi))
//   s_i     = sin(ang_i) + EPS        (sin>0 on this range)
//   out_j   = radius * prod_{i<j} s_i * (|cos ang_j|+EPS) * sign(cos ang_j),  j<512
//   out_512 = radius * prod_{i<512} s_i
// This equals the reference's log-domain triangular matmul exactly (to fp error).

#define ROW_N   512
#define ROW_OUT 513
#define EPSF    1e-6f

__global__ __launch_bounds__(256)
void spherization_kernel(const float* __restrict__ x,
                         const float* __restrict__ scp,
                         const float* __restrict__ rdp,
                         float* __restrict__ out,
                         int rows, float A, float phiL) {
    const int wavesPerBlk = blockDim.x >> 6;
    const int row  = blockIdx.x * wavesPerBlk + (threadIdx.x >> 6);
    const int lane = threadIdx.x & 63;
    if (row >= rows) return;

    const float scaling = scp[0];
    const float radius  = rdp[0];

    const float* xr = x + (size_t)row * ROW_N;
    float* orow = out + (size_t)row * ROW_OUT;

    float carry = 1.0f;  // running product of (sin+eps) over previous chunks

#pragma unroll
    for (int c = 0; c < 2; ++c) {
        // coalesced float4 load: wave covers 1024B contiguous
        const float4 v = ((const float4*)xr)[c * 64 + lane];
        float xe[4] = {v.x, v.y, v.z, v.w};
        float s[4], cs[4];
        float p = 1.0f;
#pragma unroll
        for (int j = 0; j < 4; ++j) {
            float t   = scaling * xe[j];
            float sig = 1.0f / (1.0f + __expf(-t));
            float ang = A * sig + phiL;          // in [phiL, pi-phiL]
            float sn  = __sinf(ang);
            float csn = __cosf(ang);
            s[j]  = sn + EPSF;
            cs[j] = csn;
            p *= s[j];
        }

        // wave-wide inclusive multiplicative scan of per-lane products
        float inc = p;
#pragma unroll
        for (int off = 1; off < 64; off <<= 1) {
            float up = __shfl_up(inc, off, 64);
            if (lane >= off) inc *= up;
        }
        // exclusive prefix for this lane
        float ex = __shfl_up(inc, 1, 64);
        if (lane == 0) ex = 1.0f;
        float chunkTotal = __shfl(inc, 63, 64);

        float prefix = carry * ex;
#pragma unroll
        for (int j = 0; j < 4; ++j) {
            float mag = radius * prefix * (fabsf(cs[j]) + EPSF);
            orow[c * 256 + lane * 4 + j] = (cs[j] < 0.0f) ? -mag : mag;
            prefix *= s[j];
        }
        carry *= chunkTotal;
    }

    if (lane == 0) orow[ROW_N] = radius * carry;  // last coordinate, sign forced +1
}

extern "C" void kernel_launch(void* const* d_in, const int* in_sizes, int n_in,
                              void* d_out, int out_size, void* d_ws, size_t ws_size,
                              hipStream_t stream) {
    const float* x   = (const float*)d_in[0];
    const float* scp = (const float*)d_in[1];
    const float* rdp = (const float*)d_in[2];
    float* out = (float*)d_out;

    const int rows = in_sizes[0] / ROW_N;   // 65536

    // Host-side double-precision constants, matching the Python reference:
    //   PHI_L = min(asin(1e-6 ** (1/512)), (3.141592/2)*(1-0.01))
    const double PI_REF = 3.141592;
    const double dpow   = std::pow(1e-6, 1.0 / 512.0);
    double phiL_d = std::asin(dpow);
    const double ub = PI_REF / 2.0 * (1.0 - 0.01);
    if (ub < phiL_d) phiL_d = ub;
    const float phiL = (float)phiL_d;
    const float A    = (float)(PI_REF - 2.0 * phiL_d);

    const int wavesPerBlk = 4;                       // 256 threads
    const int grid = (rows + wavesPerBlk - 1) / wavesPerBlk;
    spherization_kernel<<<grid, 256, 0, stream>>>(x, scp, rdp, out, rows, A, phiL);
}